// Round 2
// baseline (180.915 us; speedup 1.0000x reference)
//
#include <hip/hip_runtime.h>
#include <hip/hip_bf16.h>
#include <math.h>

#define B_ROWS 4096
#define D_DIM 512
#define TWO_B 8192
#define HW_N 256
#define BASE_T 0.07f
#define ALPHA_C 0.5f
#define LOG2E 1.44269504088896340736f

typedef __bf16 v8bf __attribute__((ext_vector_type(8)));
typedef float v4f __attribute__((ext_vector_type(4)));

// ---------------------------------------------------------------------------
// Kernel 1: normalize, temps, pos_sim
// One block (256 thr) per sample row b.
// inv_temp is pre-scaled by log2(e) so gram epilogue can use exp2 directly.
// pos[] stays in natural-log units (it is subtracted from ln(denom)).
// ---------------------------------------------------------------------------
__global__ __launch_bounds__(256) void prep_kernel(
    const float* __restrict__ emb1, const float* __restrict__ emb2,
    const float* __restrict__ att, __hip_bfloat16* __restrict__ X,
    float* __restrict__ inv_temp, float* __restrict__ pos)
{
    const int b = blockIdx.x;
    const int t = threadIdx.x;
    const float* e1 = emb1 + (size_t)b * D_DIM;
    const float* e2 = emb2 + (size_t)b * D_DIM;
    float a1 = e1[t], c1 = e1[t + 256];
    float a2 = e2[t], c2 = e2[t + 256];
    float av = att[(size_t)b * HW_N + t];
    float s1 = a1 * a1 + c1 * c1;
    float s2 = a2 * a2 + c2 * c2;
    float s12 = a1 * a2 + c1 * c2;
    #pragma unroll
    for (int m = 1; m < 64; m <<= 1) {
        s1  += __shfl_xor(s1, m, 64);
        s2  += __shfl_xor(s2, m, 64);
        s12 += __shfl_xor(s12, m, 64);
        av  += __shfl_xor(av, m, 64);
    }
    __shared__ float red[4][4];
    const int w = t >> 6, lane = t & 63;
    if (lane == 0) { red[w][0] = s1; red[w][1] = s2; red[w][2] = s12; red[w][3] = av; }
    __syncthreads();
    const float T1  = red[0][0] + red[1][0] + red[2][0] + red[3][0];
    const float T2  = red[0][1] + red[1][1] + red[2][1] + red[3][1];
    const float T12 = red[0][2] + red[1][2] + red[2][2] + red[3][2];
    const float Ta  = red[0][3] + red[1][3] + red[2][3] + red[3][3];
    const float n1 = fmaxf(sqrtf(T1), 1e-12f);
    const float n2 = fmaxf(sqrtf(T2), 1e-12f);
    const float i1 = 1.0f / n1, i2 = 1.0f / n2;
    const float it = 1.0f / (BASE_T * (1.0f + ALPHA_C * (Ta * (1.0f / 256.0f))));
    __hip_bfloat16* x1 = X + (size_t)b * D_DIM;
    __hip_bfloat16* x2 = X + (size_t)(b + B_ROWS) * D_DIM;
    x1[t]       = __float2bfloat16(a1 * i1);
    x1[t + 256] = __float2bfloat16(c1 * i1);
    x2[t]       = __float2bfloat16(a2 * i2);
    x2[t + 256] = __float2bfloat16(c2 * i2);
    if (t == 0) {
        inv_temp[b] = it * LOG2E;            // exp2 units
        inv_temp[b + B_ROWS] = it * LOG2E;
        pos[b] = (T12 * i1 * i2) * it;       // ln units
    }
}

// ---------------------------------------------------------------------------
// Kernel 2: symmetric Gram tiles (rb<=cb only) + fused exp row/col sums.
// 128x128 tile, BK=64, 4 waves 2x2, XOR-swizzled LDS (bank-conflict-free).
// partial slice scheme: row-sums -> slice 2*cb+wn, col-sums -> slice 2*rb+wm.
// Every entry of partial[128][8192] written exactly once.
// ---------------------------------------------------------------------------
__device__ __forceinline__ void gload_lds16(const void* g, void* s) {
    __builtin_amdgcn_global_load_lds(
        (const __attribute__((address_space(1))) unsigned int*)g,
        (__attribute__((address_space(3))) unsigned int*)s,
        16, 0, 0);
}

__global__ __launch_bounds__(256) void gram_kernel(
    const __hip_bfloat16* __restrict__ X,
    const float* __restrict__ inv_temp,
    float* __restrict__ partial)
{
    const int cb = blockIdx.x;
    const int rb = blockIdx.y;
    if (rb > cb) return;                      // triangular grid

    __shared__ __hip_bfloat16 smA[128 * 64];  // 16 KB, BK=64
    __shared__ __hip_bfloat16 smB[128 * 64];

    const int rowBase = rb * 128;
    const int colBase = cb * 128;

    const int tid  = threadIdx.x;
    const int w    = tid >> 6;
    const int lane = tid & 63;
    const int quad = lane >> 4;
    const int t    = lane & 15;
    const int wm   = w >> 1;
    const int wn   = w & 1;

    // staging lane roles: 8 rows x 8 chunks(16B) per 64-lane call (1 KB)
    const int srow   = lane >> 3;             // 0..7
    const int schunk = lane & 7;              // 0..7
    const int gchunk = schunk ^ srow;         // XOR swizzle (store side)

    v4f acc[4][4];
    #pragma unroll
    for (int a = 0; a < 4; a++)
        #pragma unroll
        for (int b2 = 0; b2 < 4; b2++)
            acc[a][b2] = v4f{0.0f, 0.0f, 0.0f, 0.0f};

    const __hip_bfloat16* Arow0 = X + (size_t)rowBase * D_DIM;
    const __hip_bfloat16* Brow0 = X + (size_t)colBase * D_DIM;

    for (int kk = 0; kk < D_DIM; kk += 64) {
        #pragma unroll
        for (int c = 0; c < 4; c++) {
            const int g = w * 4 + c;          // 8-row group id, wave-uniform
            const int r = g * 8 + srow;
            gload_lds16(Arow0 + (size_t)r * D_DIM + kk + gchunk * 8, &smA[g * 512]);
            gload_lds16(Brow0 + (size_t)r * D_DIM + kk + gchunk * 8, &smB[g * 512]);
        }
        __syncthreads();

        #pragma unroll
        for (int s = 0; s < 2; s++) {
            v8bf af[4], bf[4];
            #pragma unroll
            for (int mi = 0; mi < 4; mi++) {
                const int row = wm * 64 + mi * 16 + t;
                const int p = (s * 4 + quad) ^ (t & 7);   // XOR swizzle (read)
                af[mi] = *(const v8bf*)&smA[row * 64 + p * 8];
            }
            #pragma unroll
            for (int ni = 0; ni < 4; ni++) {
                const int col = wn * 64 + ni * 16 + t;
                const int p = (s * 4 + quad) ^ (t & 7);
                bf[ni] = *(const v8bf*)&smB[col * 64 + p * 8];
            }
            #pragma unroll
            for (int mi = 0; mi < 4; mi++)
                #pragma unroll
                for (int ni = 0; ni < 4; ni++)
                    acc[mi][ni] = __builtin_amdgcn_mfma_f32_16x16x32_bf16(
                        af[mi], bf[ni], acc[mi][ni], 0, 0, 0);
        }
        __syncthreads();
    }

    // ---- Epilogue 1: row sums (exp with temp_i), slice 2*cb+wn ----
    float* prow = partial + (size_t)(cb * 2 + wn) * TWO_B;
    #pragma unroll
    for (int mi = 0; mi < 4; mi++) {
        #pragma unroll
        for (int r = 0; r < 4; r++) {
            const int i = rowBase + wm * 64 + mi * 16 + quad * 4 + r;
            const float it = inv_temp[i];
            float s = 0.0f;
            #pragma unroll
            for (int ni = 0; ni < 4; ni++) {
                const int j = colBase + wn * 64 + ni * 16 + t;
                const float v = exp2f(acc[mi][ni][r] * it);
                s += (i == j) ? 0.0f : v;
            }
            s += __shfl_xor(s, 1, 64);
            s += __shfl_xor(s, 2, 64);
            s += __shfl_xor(s, 4, 64);
            s += __shfl_xor(s, 8, 64);
            if (t == 0) prow[i] = s;
        }
    }

    // ---- Epilogue 2 (off-diag only): col sums (exp with temp_j), slice 2*rb+wm
    if (rb != cb) {
        float itj[4];
        float cs[4] = {0.0f, 0.0f, 0.0f, 0.0f};
        #pragma unroll
        for (int ni = 0; ni < 4; ni++)
            itj[ni] = inv_temp[colBase + wn * 64 + ni * 16 + t];
        #pragma unroll
        for (int mi = 0; mi < 4; mi++)
            #pragma unroll
            for (int r = 0; r < 4; r++)
                #pragma unroll
                for (int ni = 0; ni < 4; ni++)
                    cs[ni] += exp2f(acc[mi][ni][r] * itj[ni]);
        float* pcol = partial + (size_t)(rb * 2 + wm) * TWO_B;
        #pragma unroll
        for (int ni = 0; ni < 4; ni++) {
            cs[ni] += __shfl_xor(cs[ni], 16, 64);
            cs[ni] += __shfl_xor(cs[ni], 32, 64);
            if (quad == 0) pcol[colBase + wn * 64 + ni * 16 + t] = cs[ni];
        }
    }
}

// ---------------------------------------------------------------------------
// Kernel 3a: denom = sum of 128 slices; loss_i = log(denom) - pos; block sums
// ---------------------------------------------------------------------------
__global__ __launch_bounds__(256) void finish1(
    const float* __restrict__ partial, const float* __restrict__ pos,
    float* __restrict__ blockSums)
{
    const int i = blockIdx.x * 256 + threadIdx.x;
    float d = 0.0f;
    for (int s = 0; s < 128; s++) d += partial[(size_t)s * TWO_B + i];
    float li = logf(d) - pos[i & (B_ROWS - 1)];
    #pragma unroll
    for (int m = 1; m < 64; m <<= 1) li += __shfl_xor(li, m, 64);
    __shared__ float red[4];
    const int w = threadIdx.x >> 6, lane = threadIdx.x & 63;
    if (lane == 0) red[w] = li;
    __syncthreads();
    if (threadIdx.x == 0) blockSums[blockIdx.x] = red[0] + red[1] + red[2] + red[3];
}

// ---------------------------------------------------------------------------
// Kernel 3b: final scalar
// ---------------------------------------------------------------------------
__global__ void finish2(const float* __restrict__ blockSums, float* __restrict__ out)
{
    const int lane = threadIdx.x;
    float v = (lane < 32) ? blockSums[lane] : 0.0f;
    #pragma unroll
    for (int m = 1; m < 64; m <<= 1) v += __shfl_xor(v, m, 64);
    if (lane == 0) out[0] = v * (1.0f / 8192.0f);
}

// ---------------------------------------------------------------------------
extern "C" void kernel_launch(void* const* d_in, const int* in_sizes, int n_in,
                              void* d_out, int out_size, void* d_ws, size_t ws_size,
                              hipStream_t stream) {
    const float* emb1 = (const float*)d_in[0];
    const float* emb2 = (const float*)d_in[1];
    const float* att  = (const float*)d_in[2];
    float* out = (float*)d_out;

    char* ws = (char*)d_ws;
    // layout: X bf16 [8192*512] = 8,388,608 B
    //         inv_temp f32 [8192] -> +32,768
    //         pos f32 [4096]      -> +16,384
    //         partial f32 [128*8192] -> +4,194,304
    //         blockSums f32 [32]  -> +128
    __hip_bfloat16* X  = (__hip_bfloat16*)ws;
    float* inv_temp    = (float*)(ws + 8388608);
    float* pos         = (float*)(ws + 8388608 + 32768);
    float* partial     = (float*)(ws + 8388608 + 32768 + 16384);
    float* blockSums   = (float*)(ws + 8388608 + 32768 + 16384 + 4194304);

    prep_kernel<<<B_ROWS, 256, 0, stream>>>(emb1, emb2, att, X, inv_temp, pos);
    dim3 g2(TWO_B / 128, TWO_B / 128);
    gram_kernel<<<g2, 256, 0, stream>>>(X, inv_temp, partial);
    finish1<<<TWO_B / 256, 256, 0, stream>>>(partial, pos, blockSums);
    finish2<<<1, 64, 0, stream>>>(blockSums, out);
}

// Round 3
// 180.273 us; speedup vs baseline: 1.0036x; 1.0036x over previous
//
#include <hip/hip_runtime.h>
#include <hip/hip_bf16.h>
#include <math.h>

#define B_ROWS 4096
#define D_DIM 512
#define TWO_B 8192
#define HW_N 256
#define BASE_T 0.07f
#define ALPHA_C 0.5f
#define LOG2E 1.44269504088896340736f

typedef __bf16 v8bf __attribute__((ext_vector_type(8)));
typedef float v4f __attribute__((ext_vector_type(4)));

__device__ __forceinline__ float fast_exp2(float x) {
#if __has_builtin(__builtin_amdgcn_exp2f)
    return __builtin_amdgcn_exp2f(x);
#else
    return exp2f(x);
#endif
}

// ---------------------------------------------------------------------------
// Kernel 1: normalize, temps, pos_sim. One block (256 thr) per sample row b.
// inv_temp pre-scaled by log2(e) so gram epilogue uses raw v_exp_f32.
// ---------------------------------------------------------------------------
__global__ __launch_bounds__(256) void prep_kernel(
    const float* __restrict__ emb1, const float* __restrict__ emb2,
    const float* __restrict__ att, __hip_bfloat16* __restrict__ X,
    float* __restrict__ inv_temp, float* __restrict__ pos)
{
    const int b = blockIdx.x;
    const int t = threadIdx.x;
    const float* e1 = emb1 + (size_t)b * D_DIM;
    const float* e2 = emb2 + (size_t)b * D_DIM;
    float a1 = e1[t], c1 = e1[t + 256];
    float a2 = e2[t], c2 = e2[t + 256];
    float av = att[(size_t)b * HW_N + t];
    float s1 = a1 * a1 + c1 * c1;
    float s2 = a2 * a2 + c2 * c2;
    float s12 = a1 * a2 + c1 * c2;
    #pragma unroll
    for (int m = 1; m < 64; m <<= 1) {
        s1  += __shfl_xor(s1, m, 64);
        s2  += __shfl_xor(s2, m, 64);
        s12 += __shfl_xor(s12, m, 64);
        av  += __shfl_xor(av, m, 64);
    }
    __shared__ float red[4][4];
    const int w = t >> 6, lane = t & 63;
    if (lane == 0) { red[w][0] = s1; red[w][1] = s2; red[w][2] = s12; red[w][3] = av; }
    __syncthreads();
    const float T1  = red[0][0] + red[1][0] + red[2][0] + red[3][0];
    const float T2  = red[0][1] + red[1][1] + red[2][1] + red[3][1];
    const float T12 = red[0][2] + red[1][2] + red[2][2] + red[3][2];
    const float Ta  = red[0][3] + red[1][3] + red[2][3] + red[3][3];
    const float i1 = 1.0f / fmaxf(sqrtf(T1), 1e-12f);
    const float i2 = 1.0f / fmaxf(sqrtf(T2), 1e-12f);
    const float it = 1.0f / (BASE_T * (1.0f + ALPHA_C * (Ta * (1.0f / 256.0f))));
    __hip_bfloat16* x1 = X + (size_t)b * D_DIM;
    __hip_bfloat16* x2 = X + (size_t)(b + B_ROWS) * D_DIM;
    x1[t]       = __float2bfloat16(a1 * i1);
    x1[t + 256] = __float2bfloat16(c1 * i1);
    x2[t]       = __float2bfloat16(a2 * i2);
    x2[t + 256] = __float2bfloat16(c2 * i2);
    if (t == 0) {
        inv_temp[b] = it * LOG2E;
        inv_temp[b + B_ROWS] = it * LOG2E;
        pos[b] = (T12 * i1 * i2) * it;       // ln units
    }
}

// ---------------------------------------------------------------------------
// Kernel 2: triangular Gram (rb<=cb), register-prefetch pipelined K-loop.
// 128x128 tile, BK=32, double-buffered LDS (stride 40 elems: conflict-free
// b128 without swizzle), ONE barrier per K-iteration. Fused exp row/col sums.
// ---------------------------------------------------------------------------
#define LSTRIDE 40
#define LBUF (128 * LSTRIDE)

__global__ __launch_bounds__(256) void gram_kernel(
    const __hip_bfloat16* __restrict__ X,
    const float* __restrict__ inv_temp,
    float* __restrict__ partial)
{
    // --- triangular index: bid -> (rb, cb), rb <= cb, row-major upper tri ---
    const int bid = blockIdx.x;
    int rb = (int)((129.0f - sqrtf(129.0f * 129.0f - 8.0f * (float)bid)) * 0.5f);
    rb = rb < 0 ? 0 : (rb > 63 ? 63 : rb);
    while (rb > 0 && (rb * (129 - rb)) / 2 > bid) rb--;
    while (rb < 63 && ((rb + 1) * (129 - (rb + 1))) / 2 <= bid) rb++;
    const int cb = rb + (bid - (rb * (129 - rb)) / 2);

    __shared__ __hip_bfloat16 smA[2 * LBUF];   // 20 KB
    __shared__ __hip_bfloat16 smB[2 * LBUF];   // 20 KB

    const int rowBase = rb * 128;
    const int colBase = cb * 128;

    const int tid  = threadIdx.x;
    const int w    = tid >> 6;
    const int lane = tid & 63;
    const int quad = lane >> 4;
    const int t    = lane & 15;
    const int wm   = w >> 1;
    const int wn   = w & 1;

    // staging roles: threads 0-127 stage A rows, 128-255 stage B rows
    const int srow = tid & 127;
    const __hip_bfloat16* gsrc =
        ((tid >> 7) ? (X + (size_t)colBase * D_DIM) : (X + (size_t)rowBase * D_DIM))
        + (size_t)srow * D_DIM;
    __hip_bfloat16* sdst = ((tid >> 7) ? smB : smA) + srow * LSTRIDE;

    v4f acc[4][4];
    #pragma unroll
    for (int a = 0; a < 4; a++)
        #pragma unroll
        for (int b2 = 0; b2 < 4; b2++)
            acc[a][b2] = v4f{0.0f, 0.0f, 0.0f, 0.0f};

    v4f rg[2];   // 32B/thread prefetch (one BK=32 chunk of this thread's row)
    rg[0] = *(const v4f*)(gsrc);
    rg[1] = *(const v4f*)(gsrc + 8);

    int p = 0;
    for (int it = 0; it < 16; ++it) {
        // commit prefetched chunk to LDS buffer p
        *(v4f*)&sdst[(size_t)p * LBUF]     = rg[0];
        *(v4f*)&sdst[(size_t)p * LBUF + 8] = rg[1];
        // second half of the 64B row-chunk loads directly (short pipe):
        {
            const __hip_bfloat16* g = gsrc + it * 32;
            v4f r2 = *(const v4f*)(g + 16);
            v4f r3 = *(const v4f*)(g + 24);
            *(v4f*)&sdst[(size_t)p * LBUF + 16] = r2;
            *(v4f*)&sdst[(size_t)p * LBUF + 24] = r3;
        }
        __syncthreads();
        if (it < 15) {   // prefetch next tile's first 32B (latency hidden by compute)
            const __hip_bfloat16* g = gsrc + (it + 1) * 32;
            rg[0] = *(const v4f*)(g);
            rg[1] = *(const v4f*)(g + 8);
        }
        // compute from buffer p
        const __hip_bfloat16* bA = smA + (size_t)p * LBUF;
        const __hip_bfloat16* bB = smB + (size_t)p * LBUF;
        v8bf af[4], bf[4];
        #pragma unroll
        for (int mi = 0; mi < 4; mi++)
            af[mi] = *(const v8bf*)&bA[(wm * 64 + mi * 16 + t) * LSTRIDE + quad * 8];
        #pragma unroll
        for (int ni = 0; ni < 4; ni++)
            bf[ni] = *(const v8bf*)&bB[(wn * 64 + ni * 16 + t) * LSTRIDE + quad * 8];
        #pragma unroll
        for (int mi = 0; mi < 4; mi++)
            #pragma unroll
            for (int ni = 0; ni < 4; ni++)
                acc[mi][ni] = __builtin_amdgcn_mfma_f32_16x16x32_bf16(
                    af[mi], bf[ni], acc[mi][ni], 0, 0, 0);
        p ^= 1;
    }

    // ---- Epilogue 1: row sums (temp_i), slice 2*cb+wn ----
    v4f itv[4];
    #pragma unroll
    for (int mi = 0; mi < 4; mi++)
        itv[mi] = *(const v4f*)&inv_temp[rowBase + wm * 64 + mi * 16 + quad * 4];

    float* prow = partial + (size_t)(cb * 2 + wn) * TWO_B;
    #pragma unroll
    for (int mi = 0; mi < 4; mi++) {
        #pragma unroll
        for (int r = 0; r < 4; r++) {
            const int i = rowBase + wm * 64 + mi * 16 + quad * 4 + r;
            const float it = itv[mi][r];
            float s = 0.0f;
            #pragma unroll
            for (int ni = 0; ni < 4; ni++) {
                const int j = colBase + wn * 64 + ni * 16 + t;
                const float v = fast_exp2(acc[mi][ni][r] * it);
                s += (i == j) ? 0.0f : v;
            }
            s += __shfl_xor(s, 1, 64);
            s += __shfl_xor(s, 2, 64);
            s += __shfl_xor(s, 4, 64);
            s += __shfl_xor(s, 8, 64);
            if (t == 0) prow[i] = s;
        }
    }

    // ---- Epilogue 2 (off-diag): col sums (temp_j), slice 2*rb+wm ----
    if (rb != cb) {
        float itj[4];
        float cs[4] = {0.0f, 0.0f, 0.0f, 0.0f};
        #pragma unroll
        for (int ni = 0; ni < 4; ni++)
            itj[ni] = inv_temp[colBase + wn * 64 + ni * 16 + t];
        #pragma unroll
        for (int mi = 0; mi < 4; mi++)
            #pragma unroll
            for (int r = 0; r < 4; r++)
                #pragma unroll
                for (int ni = 0; ni < 4; ni++)
                    cs[ni] += fast_exp2(acc[mi][ni][r] * itj[ni]);
        float* pcol = partial + (size_t)(rb * 2 + wm) * TWO_B;
        #pragma unroll
        for (int ni = 0; ni < 4; ni++) {
            cs[ni] += __shfl_xor(cs[ni], 16, 64);
            cs[ni] += __shfl_xor(cs[ni], 32, 64);
            if (quad == 0) pcol[colBase + wn * 64 + ni * 16 + t] = cs[ni];
        }
    }
}

// ---------------------------------------------------------------------------
// Kernel 3a: denom = sum of 128 slices; loss_i = log(denom) - pos; block sums
// ---------------------------------------------------------------------------
__global__ __launch_bounds__(256) void finish1(
    const float* __restrict__ partial, const float* __restrict__ pos,
    float* __restrict__ blockSums)
{
    const int i = blockIdx.x * 256 + threadIdx.x;
    float d = 0.0f;
    #pragma unroll 8
    for (int s = 0; s < 128; s++) d += partial[(size_t)s * TWO_B + i];
    float li = logf(d) - pos[i & (B_ROWS - 1)];
    #pragma unroll
    for (int m = 1; m < 64; m <<= 1) li += __shfl_xor(li, m, 64);
    __shared__ float red[4];
    const int w = threadIdx.x >> 6, lane = threadIdx.x & 63;
    if (lane == 0) red[w] = li;
    __syncthreads();
    if (threadIdx.x == 0) blockSums[blockIdx.x] = red[0] + red[1] + red[2] + red[3];
}

__global__ void finish2(const float* __restrict__ blockSums, float* __restrict__ out)
{
    const int lane = threadIdx.x;
    float v = (lane < 32) ? blockSums[lane] : 0.0f;
    #pragma unroll
    for (int m = 1; m < 64; m <<= 1) v += __shfl_xor(v, m, 64);
    if (lane == 0) out[0] = v * (1.0f / 8192.0f);
}

// ---------------------------------------------------------------------------
extern "C" void kernel_launch(void* const* d_in, const int* in_sizes, int n_in,
                              void* d_out, int out_size, void* d_ws, size_t ws_size,
                              hipStream_t stream) {
    const float* emb1 = (const float*)d_in[0];
    const float* emb2 = (const float*)d_in[1];
    const float* att  = (const float*)d_in[2];
    float* out = (float*)d_out;

    char* ws = (char*)d_ws;
    __hip_bfloat16* X  = (__hip_bfloat16*)ws;
    float* inv_temp    = (float*)(ws + 8388608);
    float* pos         = (float*)(ws + 8388608 + 32768);
    float* partial     = (float*)(ws + 8388608 + 32768 + 16384);
    float* blockSums   = (float*)(ws + 8388608 + 32768 + 16384 + 4194304);

    prep_kernel<<<B_ROWS, 256, 0, stream>>>(emb1, emb2, att, X, inv_temp, pos);
    gram_kernel<<<2080, 256, 0, stream>>>(X, inv_temp, partial);
    finish1<<<TWO_B / 256, 256, 0, stream>>>(partial, pos, blockSums);
    finish2<<<1, 64, 0, stream>>>(blockSums, out);
}

// Round 4
// 143.401 us; speedup vs baseline: 1.2616x; 1.2571x over previous
//
#include <hip/hip_runtime.h>
#include <hip/hip_bf16.h>
#include <math.h>

#define B_ROWS 4096
#define D_DIM 512
#define TWO_B 8192
#define HW_N 256
#define BASE_T 0.07f
#define ALPHA_C 0.5f
#define LOG2E 1.44269504088896340736f

typedef __bf16 v8bf __attribute__((ext_vector_type(8)));
typedef float v4f __attribute__((ext_vector_type(4)));

__device__ __forceinline__ float fast_exp2(float x) {
#if __has_builtin(__builtin_amdgcn_exp2f)
    return __builtin_amdgcn_exp2f(x);
#else
    return exp2f(x);
#endif
}

// ---------------------------------------------------------------------------
// Kernel 1: normalize, temps, pos_sim. One block (256 thr) per sample row b.
// ---------------------------------------------------------------------------
__global__ __launch_bounds__(256) void prep_kernel(
    const float* __restrict__ emb1, const float* __restrict__ emb2,
    const float* __restrict__ att, __hip_bfloat16* __restrict__ X,
    float* __restrict__ inv_temp, float* __restrict__ pos)
{
    const int b = blockIdx.x;
    const int t = threadIdx.x;
    const float* e1 = emb1 + (size_t)b * D_DIM;
    const float* e2 = emb2 + (size_t)b * D_DIM;
    float a1 = e1[t], c1 = e1[t + 256];
    float a2 = e2[t], c2 = e2[t + 256];
    float av = att[(size_t)b * HW_N + t];
    float s1 = a1 * a1 + c1 * c1;
    float s2 = a2 * a2 + c2 * c2;
    float s12 = a1 * a2 + c1 * c2;
    #pragma unroll
    for (int m = 1; m < 64; m <<= 1) {
        s1  += __shfl_xor(s1, m, 64);
        s2  += __shfl_xor(s2, m, 64);
        s12 += __shfl_xor(s12, m, 64);
        av  += __shfl_xor(av, m, 64);
    }
    __shared__ float red[4][4];
    const int w = t >> 6, lane = t & 63;
    if (lane == 0) { red[w][0] = s1; red[w][1] = s2; red[w][2] = s12; red[w][3] = av; }
    __syncthreads();
    const float T1  = red[0][0] + red[1][0] + red[2][0] + red[3][0];
    const float T2  = red[0][1] + red[1][1] + red[2][1] + red[3][1];
    const float T12 = red[0][2] + red[1][2] + red[2][2] + red[3][2];
    const float Ta  = red[0][3] + red[1][3] + red[2][3] + red[3][3];
    const float i1 = 1.0f / fmaxf(sqrtf(T1), 1e-12f);
    const float i2 = 1.0f / fmaxf(sqrtf(T2), 1e-12f);
    const float it = 1.0f / (BASE_T * (1.0f + ALPHA_C * (Ta * (1.0f / 256.0f))));
    __hip_bfloat16* x1 = X + (size_t)b * D_DIM;
    __hip_bfloat16* x2 = X + (size_t)(b + B_ROWS) * D_DIM;
    x1[t]       = __float2bfloat16(a1 * i1);
    x1[t + 256] = __float2bfloat16(c1 * i1);
    x2[t]       = __float2bfloat16(a2 * i2);
    x2[t + 256] = __float2bfloat16(c2 * i2);
    if (t == 0) {
        inv_temp[b] = it * LOG2E;
        inv_temp[b + B_ROWS] = it * LOG2E;
        pos[b] = (T12 * i1 * i2) * it;       // ln units
    }
}

// ---------------------------------------------------------------------------
// Kernel 2: triangular Gram (rb<=cb). BK=128 -> only 4 glds phases.
// LDS 64KB single-buffered (2 blocks/CU). XOR-swizzled layout: chunk c of
// row r stored at position c^(r&15) (swizzle applied on the GLOBAL address,
// since global_load_lds writes lane-linear). Read p=(s*4+quad)^t: 16 distinct
// positions -> conflict-free b128. Fused exp row/col sums.
// ---------------------------------------------------------------------------
__device__ __forceinline__ void gload_lds16(const void* g, void* s) {
    __builtin_amdgcn_global_load_lds(
        (const __attribute__((address_space(1))) unsigned int*)g,
        (__attribute__((address_space(3))) unsigned int*)s,
        16, 0, 0);
}

__global__ __launch_bounds__(256) void gram_kernel(
    const __hip_bfloat16* __restrict__ X,
    const float* __restrict__ inv_temp,
    float* __restrict__ partial)
{
    // --- triangular index: bid -> (rb, cb), rb <= cb ---
    const int bid = blockIdx.x;
    int rb = (int)((129.0f - sqrtf(129.0f * 129.0f - 8.0f * (float)bid)) * 0.5f);
    rb = rb < 0 ? 0 : (rb > 63 ? 63 : rb);
    while (rb > 0 && (rb * (129 - rb)) / 2 > bid) rb--;
    while (rb < 63 && ((rb + 1) * (129 - (rb + 1))) / 2 <= bid) rb++;
    const int cb = rb + (bid - (rb * (129 - rb)) / 2);

    // 128 rows x 128 k-elems (256 B/row) each: 32 KB + 32 KB = 64 KB total
    __shared__ __hip_bfloat16 smA[128 * 128];
    __shared__ __hip_bfloat16 smB[128 * 128];

    const int rowBase = rb * 128;
    const int colBase = cb * 128;

    const int tid  = threadIdx.x;
    const int w    = tid >> 6;
    const int lane = tid & 63;
    const int quad = lane >> 4;
    const int t    = lane & 15;
    const int wm   = w >> 1;
    const int wn   = w & 1;

    // staging roles: each glds call covers 4 rows x 16 chunks (1 KB)
    const int srow   = lane >> 4;   // 0..3
    const int schunk = lane & 15;   // 0..15

    v4f acc[4][4];
    #pragma unroll
    for (int a = 0; a < 4; a++)
        #pragma unroll
        for (int b2 = 0; b2 < 4; b2++)
            acc[a][b2] = v4f{0.0f, 0.0f, 0.0f, 0.0f};

    const __hip_bfloat16* Arow0 = X + (size_t)rowBase * D_DIM;
    const __hip_bfloat16* Brow0 = X + (size_t)colBase * D_DIM;

    for (int kk = 0; kk < D_DIM; kk += 128) {
        // stage 32 KB A + 32 KB B: per wave 8+8 glds calls, 4 rows each
        #pragma unroll
        for (int j = 0; j < 8; j++) {
            const int g = w * 8 + j;          // row group 0..31, wave-uniform
            const int r = g * 4 + srow;
            const int gc = schunk ^ (r & 15); // XOR swizzle via global addr
            gload_lds16(Arow0 + (size_t)r * D_DIM + kk + gc * 8,
                        &smA[g * 512]);       // 512 elems = 1 KB
            gload_lds16(Brow0 + (size_t)r * D_DIM + kk + gc * 8,
                        &smB[g * 512]);
        }
        __syncthreads();

        #pragma unroll
        for (int s = 0; s < 4; s++) {
            v8bf af[4], bf[4];
            #pragma unroll
            for (int mi = 0; mi < 4; mi++) {
                const int row = wm * 64 + mi * 16 + t;
                const int p = (s * 4 + quad) ^ t;
                af[mi] = *(const v8bf*)&smA[row * 128 + p * 8];
            }
            #pragma unroll
            for (int ni = 0; ni < 4; ni++) {
                const int col = wn * 64 + ni * 16 + t;
                const int p = (s * 4 + quad) ^ t;
                bf[ni] = *(const v8bf*)&smB[col * 128 + p * 8];
            }
            #pragma unroll
            for (int mi = 0; mi < 4; mi++)
                #pragma unroll
                for (int ni = 0; ni < 4; ni++)
                    acc[mi][ni] = __builtin_amdgcn_mfma_f32_16x16x32_bf16(
                        af[mi], bf[ni], acc[mi][ni], 0, 0, 0);
        }
        __syncthreads();
    }

    // ---- Epilogue 1: row sums (temp_i), slice 2*cb+wn ----
    v4f itv[4];
    #pragma unroll
    for (int mi = 0; mi < 4; mi++)
        itv[mi] = *(const v4f*)&inv_temp[rowBase + wm * 64 + mi * 16 + quad * 4];

    float* prow = partial + (size_t)(cb * 2 + wn) * TWO_B;
    #pragma unroll
    for (int mi = 0; mi < 4; mi++) {
        #pragma unroll
        for (int r = 0; r < 4; r++) {
            const int i = rowBase + wm * 64 + mi * 16 + quad * 4 + r;
            const float it = itv[mi][r];
            float s = 0.0f;
            #pragma unroll
            for (int ni = 0; ni < 4; ni++) {
                const int j = colBase + wn * 64 + ni * 16 + t;
                const float v = fast_exp2(acc[mi][ni][r] * it);
                s += (i == j) ? 0.0f : v;
            }
            s += __shfl_xor(s, 1, 64);
            s += __shfl_xor(s, 2, 64);
            s += __shfl_xor(s, 4, 64);
            s += __shfl_xor(s, 8, 64);
            if (t == 0) prow[i] = s;
        }
    }

    // ---- Epilogue 2 (off-diag): col sums (temp_j), slice 2*rb+wm ----
    if (rb != cb) {
        float itj[4];
        float cs[4] = {0.0f, 0.0f, 0.0f, 0.0f};
        #pragma unroll
        for (int ni = 0; ni < 4; ni++)
            itj[ni] = inv_temp[colBase + wn * 64 + ni * 16 + t];
        #pragma unroll
        for (int mi = 0; mi < 4; mi++)
            #pragma unroll
            for (int r = 0; r < 4; r++)
                #pragma unroll
                for (int ni = 0; ni < 4; ni++)
                    cs[ni] += fast_exp2(acc[mi][ni][r] * itj[ni]);
        float* pcol = partial + (size_t)(rb * 2 + wm) * TWO_B;
        #pragma unroll
        for (int ni = 0; ni < 4; ni++) {
            cs[ni] += __shfl_xor(cs[ni], 16, 64);
            cs[ni] += __shfl_xor(cs[ni], 32, 64);
            if (quad == 0) pcol[colBase + wn * 64 + ni * 16 + t] = cs[ni];
        }
    }
}

// ---------------------------------------------------------------------------
// Kernel 3a: denom = sum of 128 slices; loss_i = log(denom) - pos; block sums
// ---------------------------------------------------------------------------
__global__ __launch_bounds__(256) void finish1(
    const float* __restrict__ partial, const float* __restrict__ pos,
    float* __restrict__ blockSums)
{
    const int i = blockIdx.x * 256 + threadIdx.x;
    float d = 0.0f;
    #pragma unroll 8
    for (int s = 0; s < 128; s++) d += partial[(size_t)s * TWO_B + i];
    float li = logf(d) - pos[i & (B_ROWS - 1)];
    #pragma unroll
    for (int m = 1; m < 64; m <<= 1) li += __shfl_xor(li, m, 64);
    __shared__ float red[4];
    const int w = threadIdx.x >> 6, lane = threadIdx.x & 63;
    if (lane == 0) red[w] = li;
    __syncthreads();
    if (threadIdx.x == 0) blockSums[blockIdx.x] = red[0] + red[1] + red[2] + red[3];
}

__global__ void finish2(const float* __restrict__ blockSums, float* __restrict__ out)
{
    const int lane = threadIdx.x;
    float v = (lane < 32) ? blockSums[lane] : 0.0f;
    #pragma unroll
    for (int m = 1; m < 64; m <<= 1) v += __shfl_xor(v, m, 64);
    if (lane == 0) out[0] = v * (1.0f / 8192.0f);
}

// ---------------------------------------------------------------------------
extern "C" void kernel_launch(void* const* d_in, const int* in_sizes, int n_in,
                              void* d_out, int out_size, void* d_ws, size_t ws_size,
                              hipStream_t stream) {
    const float* emb1 = (const float*)d_in[0];
    const float* emb2 = (const float*)d_in[1];
    const float* att  = (const float*)d_in[2];
    float* out = (float*)d_out;

    char* ws = (char*)d_ws;
    __hip_bfloat16* X  = (__hip_bfloat16*)ws;
    float* inv_temp    = (float*)(ws + 8388608);
    float* pos         = (float*)(ws + 8388608 + 32768);
    float* partial     = (float*)(ws + 8388608 + 32768 + 16384);
    float* blockSums   = (float*)(ws + 8388608 + 32768 + 16384 + 4194304);

    prep_kernel<<<B_ROWS, 256, 0, stream>>>(emb1, emb2, att, X, inv_temp, pos);
    gram_kernel<<<2080, 256, 0, stream>>>(X, inv_temp, partial);
    finish1<<<TWO_B / 256, 256, 0, stream>>>(partial, pos, blockSums);
    finish2<<<1, 64, 0, stream>>>(blockSums, out);
}